// Round 13
// baseline (219.714 us; speedup 1.0000x reference)
//
#include <hip/hip_runtime.h>
#include <hip/hip_bf16.h>

typedef __bf16 bf16;
typedef __attribute__((ext_vector_type(8))) __bf16 bf16x8;
typedef __attribute__((ext_vector_type(4))) __bf16 bf16x4;
typedef __attribute__((ext_vector_type(4))) float f32x4;
typedef __attribute__((ext_vector_type(16))) float f32x16;
typedef __attribute__((ext_vector_type(4))) unsigned int u32x4;

#define MFMA16(a, b, c) __builtin_amdgcn_mfma_f32_16x16x32_bf16((a), (b), (c), 0, 0, 0)
#define MFMA32(a, b, c) __builtin_amdgcn_mfma_f32_32x32x16_bf16((a), (b), (c), 0, 0, 0)

constexpr int Bn = 2, Tn = 2048, Cn = 1024, Hn = 16, Dn = 64;
constexpr int Mn = Bn * Tn;
constexpr int WSZ = Cn * Cn;
constexpr int XSZ = Mn * Cn;
constexpr float LOG2E = 1.44269504088896f;

// async global->LDS, 16B/lane: LDS dest = wave-uniform base + lane*16
__device__ __forceinline__ void async_cp16(bf16* lds, const bf16* g) {
  __builtin_amdgcn_global_load_lds(
      (const __attribute__((address_space(1))) unsigned int*)g,
      (__attribute__((address_space(3))) unsigned int*)lds, 16, 0, 0);
}

__device__ __forceinline__ unsigned int cvtpk(float lo, float hi) {
  unsigned int r;
  asm("v_cvt_pk_bf16_f32 %0, %1, %2" : "=v"(r) : "v"(lo), "v"(hi));
  return r;
}

struct GemmArgs {
  const bf16* A[3];
  const bf16* Bt[3];
  const float* bias[3];
  void* out[3];
  float scale[3];
  int layout[3];   // 0 = fp32 [M,N]; 1 = bf16 [B,H,T,D]; 2 = bf16 [B,H,D,T]
};

struct PrepArgs {
  const float* W[4];
  bf16* Wt[4];
  const float* src[3];
  bf16* dst;
};

// ---------------- fused prep: activations fp32->bf16 + W transpose ----------------
// One kernel replaces convert_bf16 (6144 blocks) + transpose_convert (4096
// blocks): flattened 1D grid, block-uniform branch. Cuts one dispatch
// boundary and lets the two small memory-bound workloads overlap.
__global__ __launch_bounds__(256) void prep_kernel(PrepArgs pa) {
  __shared__ float tile[32][33];
  const int id = blockIdx.x;
  const int tid = threadIdx.x;
  if (id < 6144) {
    const int z = id >> 11;
    const float* __restrict__ s = pa.src[z];
    size_t idx = ((size_t)(id & 2047) * 256 + tid) * 8;
    float4 a = *(const float4*)&s[idx];
    float4 b = *(const float4*)&s[idx + 4];
    bf16x8 o = {(bf16)a.x, (bf16)a.y, (bf16)a.z, (bf16)a.w,
                (bf16)b.x, (bf16)b.y, (bf16)b.z, (bf16)b.w};
    *(bf16x8*)&pa.dst[(size_t)z * XSZ + idx] = o;
  } else {
    const int t = id - 6144;        // 0..4095
    const int z = t >> 10;
    const int rem = t & 1023;
    const int bxp = rem & 31, byp = rem >> 5;
    const float* __restrict__ W = pa.W[z];
    bf16* __restrict__ Wt = pa.Wt[z];
    const int tx = tid & 31, ty = tid >> 5;   // (32,8)
    const int x = bxp * 32 + tx;
    const int y0 = byp * 32;
    for (int j = 0; j < 32; j += 8) tile[ty + j][tx] = W[(y0 + ty + j) * Cn + x];
    __syncthreads();
    const int n0 = bxp * 32;
    const int k = byp * 32 + tx;
    for (int j = 0; j < 32; j += 8)
      Wt[(n0 + ty + j) * Cn + k] = (bf16)tile[tx][ty + j];
  }
}

// ---------------- GEMM: C[M,N] = A[M,K] @ Wt[N,K]^T + bias ----------------
// BM x 128 tile, BK=64, async 16B staging, XOR chunk swizzle -> conflict-free b128 reads.
// v14 (kept): y-chunked XCD swizzle (T1) — FETCH 101MB -> (verified: gemm left
// top-5, total -17us). Each XCD owns contiguous y-rows with all x; per-XCD
// working set 3MB < 4MB L2.
template <int BM>
__global__ __launch_bounds__(256) void gemm_kernel(GemmArgs args, int K) {
  constexpr int MT = BM / 32;          // m-tiles per wave
  const int z = blockIdx.z;
  const bf16* __restrict__ A = args.A[z];
  const bf16* __restrict__ Bt = args.Bt[z];
  const float* __restrict__ bias = args.bias[z];
  const float scale = args.scale[z];
  const int layout = args.layout[z];

  __shared__ bf16 As[BM * 64];
  __shared__ bf16 Bs[128 * 64];

  const int tid = threadIdx.x;
  const int w = tid >> 6, lane = tid & 63;
  const int wm = w >> 1, wn = w & 1;
  const int g = lane >> 4, l15 = lane & 15;
  const int r8 = lane >> 3, c8 = lane & 7;
  const int soff = (c8 ^ r8) << 3;
  const int kk = l15 & 7;
  const int off0 = (g ^ kk) << 3;
  const int off1 = ((4 + g) ^ kk) << 3;

  // y-chunked XCD swizzle: xcd = raw_id % 8 owns logical ids
  // [xcd*cpx, (xcd+1)*cpx) enumerated x-major -> contiguous y-rows per XCD.
  const int nx = gridDim.x;
  const int nwg = nx * gridDim.y;
  const int raw = blockIdx.x + nx * blockIdx.y;
  const int cpx = nwg >> 3;
  const int logical = (raw & 7) * cpx + (raw >> 3);
  const int bx = logical % nx, by = logical / nx;
  const int m0 = by * BM, n0 = bx * 128;

  f32x4 acc[MT][4] = {};

  for (int k0 = 0; k0 < K; k0 += 64) {
    __syncthreads();
    for (int i = 0; i < BM / 32; i++) {
      int p = w * (BM / 32) + i;
      async_cp16(&As[p * 512], &A[(size_t)(m0 + p * 8 + r8) * K + k0 + soff]);
    }
    for (int i = 0; i < 4; i++) {
      int p = w * 4 + i;
      async_cp16(&Bs[p * 512], &Bt[(size_t)(n0 + p * 8 + r8) * K + k0 + soff]);
    }
    __syncthreads();

    for (int ks = 0; ks < 2; ks++) {
      const int off = ks ? off1 : off0;
      bf16x8 af[MT], bfr[4];
      for (int mt = 0; mt < MT; mt++)
        af[mt] = *(const bf16x8*)&As[(wm * (BM / 2) + mt * 16 + l15) * 64 + off];
      for (int nt = 0; nt < 4; nt++)
        bfr[nt] = *(const bf16x8*)&Bs[(wn * 64 + nt * 16 + l15) * 64 + off];
      for (int mt = 0; mt < MT; mt++)
        for (int nt = 0; nt < 4; nt++)
          acc[mt][nt] = MFMA16(af[mt], bfr[nt], acc[mt][nt]);
    }
  }

  // epilogue: C/D layout row=(lane>>4)*4+r, col=lane&15
  for (int mt = 0; mt < MT; mt++) {
    for (int nt = 0; nt < 4; nt++) {
      int gn = n0 + wn * 64 + nt * 16 + l15;
      float bb = bias[gn];
      int gm0 = m0 + wm * (BM / 2) + mt * 16 + g * 4;
      float v[4];
      for (int r = 0; r < 4; r++) v[r] = (acc[mt][nt][r] + bb) * scale;
      if (layout == 2) {
        // V^T: bf16 [B,H,D,T]; r -> consecutive t
        int b = gm0 >> 11, t = gm0 & 2047, h = gn >> 6, d = gn & 63;
        bf16x4 ov = {(bf16)v[0], (bf16)v[1], (bf16)v[2], (bf16)v[3]};
        *(bf16x4*)&((bf16*)args.out[z])[(size_t)((b * Hn + h) * Dn + d) * Tn + t] = ov;
      } else if (layout == 1) {
        int b = gm0 >> 11, t = gm0 & 2047, h = gn >> 6, d = gn & 63;
        bf16* o = (bf16*)args.out[z] + (size_t)((b * Hn + h) * Tn + t) * Dn + d;
        for (int r = 0; r < 4; r++) o[(size_t)r * Dn] = (bf16)v[r];
      } else {
        float* o = (float*)args.out[z] + (size_t)gm0 * Cn + gn;
        for (int r = 0; r < 4; r++) o[(size_t)r * Cn] = v[r];
      }
    }
  }
}

// ---------------- Flash attention v15 ----------------
// v13 measured: occupancy doubled (31.9%) but attn only 51.5->47.5 -> LDS-
// bound, NOT occupancy-bound. SQ_LDS_BANK_CONFLICT doubled to 8.39M
// (= 13.7us/CU of stalls, 29% of wall): v13's V swizzle f(row)=row&3 was
// WRONG for 64B rows. Granule = 4*(row&1) + (chunk ^ f(row)); with f=row&3
// even rows only produce {c, c^2} -> half the granule positions unused,
// 8-deep aliasing. v15 fix: f(row) = (row>>1)&3 -> rows 0..7 cover all 8
// granules exactly once (minimum aliasing). Applied identically to the
// staging pre-swizzle (voff) and the frag-read (sw3); K swizzle unchanged.
constexpr int KVB = 32;
constexpr int NTt = Tn / KVB;   // 64 kv tiles total; 32 per half

struct PvOn  { static constexpr bool value = true;  };
struct PvOff { static constexpr bool value = false; };

__global__ __launch_bounds__(512) void attn_kernel(const bf16* __restrict__ Qh,
                                                   const bf16* __restrict__ Kh,
                                                   const bf16* __restrict__ VhT,
                                                   bf16* __restrict__ AO) {
  __shared__ char smem[32768];   // per half (16KB): K[2][2048] | V[2][2048]; reused as combine buf

  const int tid = threadIdx.x;
  const int w = tid >> 6, lane = tid & 63;
  const int qw = w & 3, half = w >> 2;
  const int l31 = lane & 31, hi = lane >> 5;
  const int id = blockIdx.x;
  const int bh = id & 31;           // low bits -> same-bh blocks share an XCD
  const int q0 = (id >> 5) * 128;
  const int t0 = half * (NTt / 2);
  const int tend = t0 + NTt / 2;
  const size_t hb = (size_t)bh * Tn * Dn;
  const size_t hbT = (size_t)bh * Dn * Tn;
  // K staging: lane -> rel row r8 = lane>>3 (8 rows/wave), chunk c8 = lane&7
  const int r8 = lane >> 3, c8 = lane & 7;
  const int soff = (c8 ^ r8) << 3;              // K global chunk pre-swizzle
  // V staging: lane -> rel row rv = lane>>2 (16 rows/wave), chunk cv = lane&3
  const int rv = lane >> 2, cv = lane & 3;
  const int voff = ((cv ^ ((rv >> 1) & 3)) << 3);  // V pre-swizzle, f(row)=(row>>1)&3
  // K-frag read addressing: row r, chunk c at (r>>3)*512 + (r&7)*64 + ((c^(r&7))<<3)
  const int sw7 = l31 & 7;
  const int baseK = ((l31 >> 3) << 9) + (sw7 << 6);
  // V-frag read addressing: row r (=l31 / +32), chunk c at r*32 + ((c^((r>>1)&3))<<3)
  const int sw3 = (l31 >> 1) & 3;
  const int baseV = l31 << 5;

  bf16* Ks = (bf16*)(smem + half * 16384);            // [2][2048]
  bf16* Vt = (bf16*)(smem + half * 16384 + 8192);     // [2][2048]

  // Q fragments (B-operand): lane owns q = q0 + qw*32 + l31
  bf16x8 qf[4];
  {
    const bf16* qp = Qh + hb + (size_t)(q0 + qw * 32 + l31) * Dn + hi * 8;
#pragma unroll
    for (int ks = 0; ks < 4; ks++) qf[ks] = *(const bf16x8*)(qp + ks * 16);
  }

  f32x16 o0 = {}, o1 = {};
  float l_run = 0.f;
  bf16x8 vf0[2], vf1[2];   // V^T frags of tile t (d 0-31 / 32-63), consumed iter t+1
  bf16x8 pfv[2];           // P frags of tile t, consumed iter t+1

  // prologue: stage tile t0 into buffer 0 (2 loads/wave: 1 K + 1 V)
  async_cp16(&Ks[qw * 512], &Kh[hb + (size_t)(t0 * KVB + qw * 8 + r8) * Dn + soff]);
  async_cp16(&Vt[qw * 512], &VhT[hbT + (size_t)(qw * 16 + rv) * Tn + t0 * KVB + voff]);
  __syncthreads();

  auto body = [&](int kt, auto pvtag) {
    constexpr bool PV = decltype(pvtag)::value;
    const int cur = kt & 1;   // t0 is even for both halves
    if (kt + 1 < tend) {
      const int nxt = cur ^ 1;
      const int t1 = (kt + 1) * KVB;
      async_cp16(&Ks[nxt * 2048 + qw * 512], &Kh[hb + (size_t)(t1 + qw * 8 + r8) * Dn + soff]);
      async_cp16(&Vt[nxt * 2048 + qw * 512], &VhT[hbT + (size_t)(qw * 16 + rv) * Tn + t1 + voff]);
    }

    // S^T = K Q^T : 32 kv rows, lane col = its q
    f32x16 sA = {};
    const bf16* ksb = &Ks[cur * 2048];
    __builtin_amdgcn_s_setprio(1);
#pragma unroll
    for (int ks = 0; ks < 4; ks++) {
      bf16x8 kf = *(const bf16x8*)(ksb + baseK + (((ks * 2 + hi) ^ sw7) << 3));
      sA = MFMA32(kf, qf[ks], sA);
    }
    __builtin_amdgcn_s_setprio(0);

    // exp(t) interleaved with PV(t-1): independent streams keep VALU+MFMA fed
    float pe[16];
    float r0 = 0.f, r1 = 0.f;
#pragma unroll
    for (int gq = 0; gq < 4; gq++) {
      float e0 = __builtin_amdgcn_exp2f(sA[gq * 4 + 0]);
      float e1 = __builtin_amdgcn_exp2f(sA[gq * 4 + 1]);
      float e2 = __builtin_amdgcn_exp2f(sA[gq * 4 + 2]);
      float e3 = __builtin_amdgcn_exp2f(sA[gq * 4 + 3]);
      pe[gq * 4 + 0] = e0; pe[gq * 4 + 1] = e1;
      pe[gq * 4 + 2] = e2; pe[gq * 4 + 3] = e3;
      r0 += e0 + e1; r1 += e2 + e3;
      if constexpr (PV) {
        if (gq < 2) o0 = MFMA32(vf0[gq], pfv[gq], o0);
        else        o1 = MFMA32(vf1[gq - 2], pfv[gq - 2], o1);
      }
    }
    l_run += r0 + r1;

    // pack P in-register (v10 scheme, half quantity): pfv[0]=kv 0..15, pfv[1]=kv 16..31
    {
      unsigned a0 = cvtpk(pe[0], pe[1]),  a1 = cvtpk(pe[2], pe[3]);
      unsigned b0 = cvtpk(pe[4], pe[5]),  b1 = cvtpk(pe[6], pe[7]);
      auto s0 = __builtin_amdgcn_permlane32_swap(a0, b0, false, false);
      auto s1 = __builtin_amdgcn_permlane32_swap(a1, b1, false, false);
      u32x4 w0 = {s0[0], s1[0], s0[1], s1[1]};
      pfv[0] = __builtin_bit_cast(bf16x8, w0);
      a0 = cvtpk(pe[8], pe[9]);   a1 = cvtpk(pe[10], pe[11]);
      b0 = cvtpk(pe[12], pe[13]); b1 = cvtpk(pe[14], pe[15]);
      s0 = __builtin_amdgcn_permlane32_swap(a0, b0, false, false);
      s1 = __builtin_amdgcn_permlane32_swap(a1, b1, false, false);
      u32x4 w1 = {s0[0], s1[0], s0[1], s1[1]};
      pfv[1] = __builtin_bit_cast(bf16x8, w1);
    }

    // V^T frags for next iter's PV; latency hidden under barrier + next S
    {
      const bf16* vtb = &Vt[cur * 2048];
#pragma unroll
      for (int ks = 0; ks < 2; ks++) {
        const int off = (((ks * 2 + hi) ^ sw3) << 3);
        vf0[ks] = *(const bf16x8*)(vtb + baseV + off);
        vf1[ks] = *(const bf16x8*)(vtb + 1024 + baseV + off);
      }
    }

    __syncthreads();  // all waves done with cur buffers; drains prefetch vmcnt
  };

  body(t0, PvOff{});
  for (int kt = t0 + 1; kt < tend; kt++) body(kt, PvOn{});

  // epilogue PV for the last tile
  __builtin_amdgcn_s_setprio(1);
#pragma unroll
  for (int ks = 0; ks < 2; ks++) {
    o0 = MFMA32(vf0[ks], pfv[ks], o0);
    o1 = MFMA32(vf1[ks], pfv[ks], o1);
  }
  __builtin_amdgcn_s_setprio(0);

  // in-block combine, two phases (32KB LDS holds 17 fields of 256 f32 = 17KB)
  float* comb = (float*)smem;
  const int cbase = qw * 64 + lane;
  if (half) {
#pragma unroll
    for (int j = 0; j < 16; j++) comb[j * 256 + cbase] = o0[j];
    comb[16 * 256 + cbase] = l_run;
  }
  __syncthreads();
  if (!half) {
#pragma unroll
    for (int j = 0; j < 16; j++) o0[j] += comb[j * 256 + cbase];
    l_run += comb[16 * 256 + cbase];
  }
  __syncthreads();
  if (half) {
#pragma unroll
    for (int j = 0; j < 16; j++) comb[j * 256 + cbase] = o1[j];
  }
  __syncthreads();
  if (!half) {
#pragma unroll
    for (int j = 0; j < 16; j++) o1[j] += comb[j * 256 + cbase];

    float l = l_run + __shfl_xor(l_run, 32);
    float inv = 1.0f / l;
    const int b = bh >> 4, h = bh & 15;
    const int q = q0 + qw * 32 + l31;
    bf16* orow = AO + (size_t)(b * Tn + q) * Cn + h * Dn;
#pragma unroll
    for (int dt = 0; dt < 2; dt++) {
      const f32x16& oo = dt ? o1 : o0;
#pragma unroll
      for (int rq = 0; rq < 4; rq++) {
        bf16x4 ov = {(bf16)(oo[rq * 4 + 0] * inv), (bf16)(oo[rq * 4 + 1] * inv),
                     (bf16)(oo[rq * 4 + 2] * inv), (bf16)(oo[rq * 4 + 3] * inv)};
        *(bf16x4*)&orow[dt * 32 + rq * 8 + hi * 4] = ov;
      }
    }
  }
}

extern "C" void kernel_launch(void* const* d_in, const int* in_sizes, int n_in,
                              void* d_out, int out_size, void* d_ws, size_t ws_size,
                              hipStream_t stream) {
  const float* query = (const float*)d_in[0];
  const float* key   = (const float*)d_in[1];
  const float* value = (const float*)d_in[2];
  const float* Wq = (const float*)d_in[3];
  const float* bq = (const float*)d_in[4];
  const float* Wk = (const float*)d_in[5];
  const float* bk = (const float*)d_in[6];
  const float* Wv = (const float*)d_in[7];
  const float* bv = (const float*)d_in[8];
  const float* Wo = (const float*)d_in[9];
  const float* bo = (const float*)d_in[10];

  bf16* p = (bf16*)d_ws;
  bf16* WqT = p; p += WSZ;
  bf16* WkT = p; p += WSZ;
  bf16* WvT = p; p += WSZ;
  bf16* WoT = p; p += WSZ;
  bf16* Xbf = p; p += 3 * XSZ;   // bf16 activations; reused as AO after QKV GEMM
  bf16* Qh = p; p += XSZ;
  bf16* Kh = p; p += XSZ;
  bf16* VhT = p; p += XSZ;
  bf16* AO = Xbf;

  PrepArgs pa;
  pa.W[0] = Wq; pa.W[1] = Wk; pa.W[2] = Wv; pa.W[3] = Wo;
  pa.Wt[0] = WqT; pa.Wt[1] = WkT; pa.Wt[2] = WvT; pa.Wt[3] = WoT;
  pa.src[0] = query; pa.src[1] = key; pa.src[2] = value;
  pa.dst = Xbf;
  prep_kernel<<<dim3(6144 + 4096), 256, 0, stream>>>(pa);

  GemmArgs ga;
  ga.A[0] = Xbf; ga.A[1] = Xbf + XSZ; ga.A[2] = Xbf + 2 * XSZ;
  ga.Bt[0] = WqT;  ga.Bt[1] = WkT; ga.Bt[2] = WvT;
  ga.bias[0] = bq; ga.bias[1] = bk; ga.bias[2] = bv;
  ga.out[0] = Qh;  ga.out[1] = Kh;  ga.out[2] = VhT;
  ga.scale[0] = 0.125f * LOG2E; ga.scale[1] = 1.0f; ga.scale[2] = 1.0f;
  ga.layout[0] = 1; ga.layout[1] = 1; ga.layout[2] = 2;
  gemm_kernel<128><<<dim3(Cn / 128, Mn / 128, 3), 256, 0, stream>>>(ga, Cn);

  attn_kernel<<<dim3(512), 512, 0, stream>>>(Qh, Kh, VhT, AO);

  GemmArgs gb;
  gb.A[0] = AO; gb.Bt[0] = WoT; gb.bias[0] = bo; gb.out[0] = d_out; gb.scale[0] = 1.0f;
  gb.layout[0] = 0;
  gb.A[1] = gb.A[2] = nullptr; gb.Bt[1] = gb.Bt[2] = nullptr;
  gb.bias[1] = gb.bias[2] = nullptr; gb.out[1] = gb.out[2] = nullptr;
  gb.scale[1] = gb.scale[2] = 1.0f; gb.layout[1] = gb.layout[2] = 0;
  gemm_kernel<64><<<dim3(Cn / 128, Mn / 64, 1), 256, 0, stream>>>(gb, Cn);
}

// Round 14
// 217.018 us; speedup vs baseline: 1.0124x; 1.0124x over previous
//
#include <hip/hip_runtime.h>
#include <hip/hip_bf16.h>

typedef __bf16 bf16;
typedef __attribute__((ext_vector_type(8))) __bf16 bf16x8;
typedef __attribute__((ext_vector_type(4))) __bf16 bf16x4;
typedef __attribute__((ext_vector_type(4))) float f32x4;
typedef __attribute__((ext_vector_type(16))) float f32x16;
typedef __attribute__((ext_vector_type(4))) unsigned int u32x4;

#define MFMA16(a, b, c) __builtin_amdgcn_mfma_f32_16x16x32_bf16((a), (b), (c), 0, 0, 0)
#define MFMA32(a, b, c) __builtin_amdgcn_mfma_f32_32x32x16_bf16((a), (b), (c), 0, 0, 0)

constexpr int Bn = 2, Tn = 2048, Cn = 1024, Hn = 16, Dn = 64;
constexpr int Mn = Bn * Tn;
constexpr int WSZ = Cn * Cn;
constexpr int XSZ = Mn * Cn;
constexpr float LOG2E = 1.44269504088896f;

// async global->LDS, 16B/lane: LDS dest = wave-uniform base + lane*16
__device__ __forceinline__ void async_cp16(bf16* lds, const bf16* g) {
  __builtin_amdgcn_global_load_lds(
      (const __attribute__((address_space(1))) unsigned int*)g,
      (__attribute__((address_space(3))) unsigned int*)lds, 16, 0, 0);
}

__device__ __forceinline__ unsigned int cvtpk(float lo, float hi) {
  unsigned int r;
  asm("v_cvt_pk_bf16_f32 %0, %1, %2" : "=v"(r) : "v"(lo), "v"(hi));
  return r;
}

struct GemmArgs {
  const bf16* A[3];
  const bf16* Bt[3];
  const float* bias[3];
  void* out[3];
  float scale[3];
  int layout[3];   // 0 = fp32 [M,N]; 1 = bf16 [B,H,T,D]; 2 = bf16 [B,H,D,T]
};

struct PrepArgs {
  const float* W[4];
  bf16* Wt[4];
  const float* src[3];
  bf16* dst;
};

// ---------------- fused prep: activations fp32->bf16 + W transpose ----------------
__global__ __launch_bounds__(256) void prep_kernel(PrepArgs pa) {
  __shared__ float tile[32][33];
  const int id = blockIdx.x;
  const int tid = threadIdx.x;
  if (id < 6144) {
    const int z = id >> 11;
    const float* __restrict__ s = pa.src[z];
    size_t idx = ((size_t)(id & 2047) * 256 + tid) * 8;
    float4 a = *(const float4*)&s[idx];
    float4 b = *(const float4*)&s[idx + 4];
    bf16x8 o = {(bf16)a.x, (bf16)a.y, (bf16)a.z, (bf16)a.w,
                (bf16)b.x, (bf16)b.y, (bf16)b.z, (bf16)b.w};
    *(bf16x8*)&pa.dst[(size_t)z * XSZ + idx] = o;
  } else {
    const int t = id - 6144;        // 0..4095
    const int z = t >> 10;
    const int rem = t & 1023;
    const int bxp = rem & 31, byp = rem >> 5;
    const float* __restrict__ W = pa.W[z];
    bf16* __restrict__ Wt = pa.Wt[z];
    const int tx = tid & 31, ty = tid >> 5;   // (32,8)
    const int x = bxp * 32 + tx;
    const int y0 = byp * 32;
    for (int j = 0; j < 32; j += 8) tile[ty + j][tx] = W[(y0 + ty + j) * Cn + x];
    __syncthreads();
    const int n0 = bxp * 32;
    const int k = byp * 32 + tx;
    for (int j = 0; j < 32; j += 8)
      Wt[(n0 + ty + j) * Cn + k] = (bf16)tile[tx][ty + j];
  }
}

// ---------------- GEMM: C[M,N] = A[M,K] @ Wt[N,K]^T + bias ----------------
// BM x 128 tile, BK=64, async 16B staging, XOR chunk swizzle.
// v14 (kept): y-chunked XCD swizzle (T1) — FETCH 101MB fixed, gemm left top-5.
// v16: DOUBLE-BUFFERED K-loop (attn-v8's proven pattern ported to the GEMM).
// Old structure exposed full HBM/L2 latency every K-iter:
//   barrier -> issue stages -> barrier(vmcnt0 drain)  [drain right after issue]
// New: stage tile k+1 into buf^1 at TOP of iter k, compute from buf, ONE
// barrier per iter. The barrier's implicit vmcnt/lgkm drain lands the
// prefetch after a full compute phase of slack; its read-retirement makes the
// next overwrite WAR-safe (same proof as attn v8). LDS 64KB (QKV) / 48KB
// (proj) -> 2 blocks/CU, ~= measured ~2.4 residency, so occupancy neutral.
template <int BM>
__global__ __launch_bounds__(256) void gemm_kernel(GemmArgs args, int K) {
  constexpr int MT = BM / 32;          // m-tiles per wave
  const int z = blockIdx.z;
  const bf16* __restrict__ A = args.A[z];
  const bf16* __restrict__ Bt = args.Bt[z];
  const float* __restrict__ bias = args.bias[z];
  const float scale = args.scale[z];
  const int layout = args.layout[z];

  __shared__ bf16 As[2][BM * 64];
  __shared__ bf16 Bs[2][128 * 64];

  const int tid = threadIdx.x;
  const int w = tid >> 6, lane = tid & 63;
  const int wm = w >> 1, wn = w & 1;
  const int g = lane >> 4, l15 = lane & 15;
  const int r8 = lane >> 3, c8 = lane & 7;
  const int soff = (c8 ^ r8) << 3;
  const int kk = l15 & 7;
  const int off0 = (g ^ kk) << 3;
  const int off1 = ((4 + g) ^ kk) << 3;

  // y-chunked XCD swizzle: xcd = raw_id % 8 owns logical ids
  // [xcd*cpx, (xcd+1)*cpx) enumerated x-major -> contiguous y-rows per XCD.
  const int nx = gridDim.x;
  const int nwg = nx * gridDim.y;
  const int raw = blockIdx.x + nx * blockIdx.y;
  const int cpx = nwg >> 3;
  const int logical = (raw & 7) * cpx + (raw >> 3);
  const int bx = logical % nx, by = logical / nx;
  const int m0 = by * BM, n0 = bx * 128;

  f32x4 acc[MT][4] = {};

  auto stage = [&](int buf, int k0) {
    for (int i = 0; i < BM / 32; i++) {
      int p = w * (BM / 32) + i;
      async_cp16(&As[buf][p * 512], &A[(size_t)(m0 + p * 8 + r8) * K + k0 + soff]);
    }
    for (int i = 0; i < 4; i++) {
      int p = w * 4 + i;
      async_cp16(&Bs[buf][p * 512], &Bt[(size_t)(n0 + p * 8 + r8) * K + k0 + soff]);
    }
  };

  stage(0, 0);
  __syncthreads();   // drains prologue stage

  const int niter = K >> 6;
  for (int it = 0; it < niter; ++it) {
    const int cur = it & 1;
    if (it + 1 < niter) stage(cur ^ 1, (it + 1) << 6);

    for (int ks = 0; ks < 2; ks++) {
      const int off = ks ? off1 : off0;
      bf16x8 af[MT], bfr[4];
      for (int mt = 0; mt < MT; mt++)
        af[mt] = *(const bf16x8*)&As[cur][(wm * (BM / 2) + mt * 16 + l15) * 64 + off];
      for (int nt = 0; nt < 4; nt++)
        bfr[nt] = *(const bf16x8*)&Bs[cur][(wn * 64 + nt * 16 + l15) * 64 + off];
      for (int mt = 0; mt < MT; mt++)
        for (int nt = 0; nt < 4; nt++)
          acc[mt][nt] = MFMA16(af[mt], bfr[nt], acc[mt][nt]);
    }
    __syncthreads();  // reads of cur retired + prefetch landed
  }

  // epilogue: C/D layout row=(lane>>4)*4+r, col=lane&15
  for (int mt = 0; mt < MT; mt++) {
    for (int nt = 0; nt < 4; nt++) {
      int gn = n0 + wn * 64 + nt * 16 + l15;
      float bb = bias[gn];
      int gm0 = m0 + wm * (BM / 2) + mt * 16 + g * 4;
      float v[4];
      for (int r = 0; r < 4; r++) v[r] = (acc[mt][nt][r] + bb) * scale;
      if (layout == 2) {
        // V^T: bf16 [B,H,D,T]; r -> consecutive t
        int b = gm0 >> 11, t = gm0 & 2047, h = gn >> 6, d = gn & 63;
        bf16x4 ov = {(bf16)v[0], (bf16)v[1], (bf16)v[2], (bf16)v[3]};
        *(bf16x4*)&((bf16*)args.out[z])[(size_t)((b * Hn + h) * Dn + d) * Tn + t] = ov;
      } else if (layout == 1) {
        int b = gm0 >> 11, t = gm0 & 2047, h = gn >> 6, d = gn & 63;
        bf16* o = (bf16*)args.out[z] + (size_t)((b * Hn + h) * Tn + t) * Dn + d;
        for (int r = 0; r < 4; r++) o[(size_t)r * Dn] = (bf16)v[r];
      } else {
        float* o = (float*)args.out[z] + (size_t)gm0 * Cn + gn;
        for (int r = 0; r < 4; r++) o[(size_t)r * Cn] = v[r];
      }
    }
  }
}

// ---------------- Flash attention v15 (unchanged from R13) ----------------
// v15 measured: V-swizzle fix halved SQ_LDS_BANK_CONFLICT (8.39M->4.19M) but
// attn only -0.6us -> conflicts off critical path. Wall = partially-overlapped
// trans(exp2 ~27us/CU) + VALU + LDS chains; near structural floor. Parked.
constexpr int KVB = 32;
constexpr int NTt = Tn / KVB;   // 64 kv tiles total; 32 per half

struct PvOn  { static constexpr bool value = true;  };
struct PvOff { static constexpr bool value = false; };

__global__ __launch_bounds__(512) void attn_kernel(const bf16* __restrict__ Qh,
                                                   const bf16* __restrict__ Kh,
                                                   const bf16* __restrict__ VhT,
                                                   bf16* __restrict__ AO) {
  __shared__ char smem[32768];   // per half (16KB): K[2][2048] | V[2][2048]; reused as combine buf

  const int tid = threadIdx.x;
  const int w = tid >> 6, lane = tid & 63;
  const int qw = w & 3, half = w >> 2;
  const int l31 = lane & 31, hi = lane >> 5;
  const int id = blockIdx.x;
  const int bh = id & 31;           // low bits -> same-bh blocks share an XCD
  const int q0 = (id >> 5) * 128;
  const int t0 = half * (NTt / 2);
  const int tend = t0 + NTt / 2;
  const size_t hb = (size_t)bh * Tn * Dn;
  const size_t hbT = (size_t)bh * Dn * Tn;
  // K staging: lane -> rel row r8 = lane>>3 (8 rows/wave), chunk c8 = lane&7
  const int r8 = lane >> 3, c8 = lane & 7;
  const int soff = (c8 ^ r8) << 3;              // K global chunk pre-swizzle
  // V staging: lane -> rel row rv = lane>>2 (16 rows/wave), chunk cv = lane&3
  const int rv = lane >> 2, cv = lane & 3;
  const int voff = ((cv ^ ((rv >> 1) & 3)) << 3);  // V pre-swizzle, f(row)=(row>>1)&3
  // K-frag read addressing: row r, chunk c at (r>>3)*512 + (r&7)*64 + ((c^(r&7))<<3)
  const int sw7 = l31 & 7;
  const int baseK = ((l31 >> 3) << 9) + (sw7 << 6);
  // V-frag read addressing: row r (=l31 / +32), chunk c at r*32 + ((c^((r>>1)&3))<<3)
  const int sw3 = (l31 >> 1) & 3;
  const int baseV = l31 << 5;

  bf16* Ks = (bf16*)(smem + half * 16384);            // [2][2048]
  bf16* Vt = (bf16*)(smem + half * 16384 + 8192);     // [2][2048]

  // Q fragments (B-operand): lane owns q = q0 + qw*32 + l31
  bf16x8 qf[4];
  {
    const bf16* qp = Qh + hb + (size_t)(q0 + qw * 32 + l31) * Dn + hi * 8;
#pragma unroll
    for (int ks = 0; ks < 4; ks++) qf[ks] = *(const bf16x8*)(qp + ks * 16);
  }

  f32x16 o0 = {}, o1 = {};
  float l_run = 0.f;
  bf16x8 vf0[2], vf1[2];   // V^T frags of tile t (d 0-31 / 32-63), consumed iter t+1
  bf16x8 pfv[2];           // P frags of tile t, consumed iter t+1

  // prologue: stage tile t0 into buffer 0 (2 loads/wave: 1 K + 1 V)
  async_cp16(&Ks[qw * 512], &Kh[hb + (size_t)(t0 * KVB + qw * 8 + r8) * Dn + soff]);
  async_cp16(&Vt[qw * 512], &VhT[hbT + (size_t)(qw * 16 + rv) * Tn + t0 * KVB + voff]);
  __syncthreads();

  auto body = [&](int kt, auto pvtag) {
    constexpr bool PV = decltype(pvtag)::value;
    const int cur = kt & 1;   // t0 is even for both halves
    if (kt + 1 < tend) {
      const int nxt = cur ^ 1;
      const int t1 = (kt + 1) * KVB;
      async_cp16(&Ks[nxt * 2048 + qw * 512], &Kh[hb + (size_t)(t1 + qw * 8 + r8) * Dn + soff]);
      async_cp16(&Vt[nxt * 2048 + qw * 512], &VhT[hbT + (size_t)(qw * 16 + rv) * Tn + t1 + voff]);
    }

    // S^T = K Q^T : 32 kv rows, lane col = its q
    f32x16 sA = {};
    const bf16* ksb = &Ks[cur * 2048];
    __builtin_amdgcn_s_setprio(1);
#pragma unroll
    for (int ks = 0; ks < 4; ks++) {
      bf16x8 kf = *(const bf16x8*)(ksb + baseK + (((ks * 2 + hi) ^ sw7) << 3));
      sA = MFMA32(kf, qf[ks], sA);
    }
    __builtin_amdgcn_s_setprio(0);

    // exp(t) interleaved with PV(t-1): independent streams keep VALU+MFMA fed
    float pe[16];
    float r0 = 0.f, r1 = 0.f;
#pragma unroll
    for (int gq = 0; gq < 4; gq++) {
      float e0 = __builtin_amdgcn_exp2f(sA[gq * 4 + 0]);
      float e1 = __builtin_amdgcn_exp2f(sA[gq * 4 + 1]);
      float e2 = __builtin_amdgcn_exp2f(sA[gq * 4 + 2]);
      float e3 = __builtin_amdgcn_exp2f(sA[gq * 4 + 3]);
      pe[gq * 4 + 0] = e0; pe[gq * 4 + 1] = e1;
      pe[gq * 4 + 2] = e2; pe[gq * 4 + 3] = e3;
      r0 += e0 + e1; r1 += e2 + e3;
      if constexpr (PV) {
        if (gq < 2) o0 = MFMA32(vf0[gq], pfv[gq], o0);
        else        o1 = MFMA32(vf1[gq - 2], pfv[gq - 2], o1);
      }
    }
    l_run += r0 + r1;

    // pack P in-register (v10 scheme, half quantity): pfv[0]=kv 0..15, pfv[1]=kv 16..31
    {
      unsigned a0 = cvtpk(pe[0], pe[1]),  a1 = cvtpk(pe[2], pe[3]);
      unsigned b0 = cvtpk(pe[4], pe[5]),  b1 = cvtpk(pe[6], pe[7]);
      auto s0 = __builtin_amdgcn_permlane32_swap(a0, b0, false, false);
      auto s1 = __builtin_amdgcn_permlane32_swap(a1, b1, false, false);
      u32x4 w0 = {s0[0], s1[0], s0[1], s1[1]};
      pfv[0] = __builtin_bit_cast(bf16x8, w0);
      a0 = cvtpk(pe[8], pe[9]);   a1 = cvtpk(pe[10], pe[11]);
      b0 = cvtpk(pe[12], pe[13]); b1 = cvtpk(pe[14], pe[15]);
      s0 = __builtin_amdgcn_permlane32_swap(a0, b0, false, false);
      s1 = __builtin_amdgcn_permlane32_swap(a1, b1, false, false);
      u32x4 w1 = {s0[0], s1[0], s0[1], s1[1]};
      pfv[1] = __builtin_bit_cast(bf16x8, w1);
    }

    // V^T frags for next iter's PV; latency hidden under barrier + next S
    {
      const bf16* vtb = &Vt[cur * 2048];
#pragma unroll
      for (int ks = 0; ks < 2; ks++) {
        const int off = (((ks * 2 + hi) ^ sw3) << 3);
        vf0[ks] = *(const bf16x8*)(vtb + baseV + off);
        vf1[ks] = *(const bf16x8*)(vtb + 1024 + baseV + off);
      }
    }

    __syncthreads();  // all waves done with cur buffers; drains prefetch vmcnt
  };

  body(t0, PvOff{});
  for (int kt = t0 + 1; kt < tend; kt++) body(kt, PvOn{});

  // epilogue PV for the last tile
  __builtin_amdgcn_s_setprio(1);
#pragma unroll
  for (int ks = 0; ks < 2; ks++) {
    o0 = MFMA32(vf0[ks], pfv[ks], o0);
    o1 = MFMA32(vf1[ks], pfv[ks], o1);
  }
  __builtin_amdgcn_s_setprio(0);

  // in-block combine, two phases (32KB LDS holds 17 fields of 256 f32 = 17KB)
  float* comb = (float*)smem;
  const int cbase = qw * 64 + lane;
  if (half) {
#pragma unroll
    for (int j = 0; j < 16; j++) comb[j * 256 + cbase] = o0[j];
    comb[16 * 256 + cbase] = l_run;
  }
  __syncthreads();
  if (!half) {
#pragma unroll
    for (int j = 0; j < 16; j++) o0[j] += comb[j * 256 + cbase];
    l_run += comb[16 * 256 + cbase];
  }
  __syncthreads();
  if (half) {
#pragma unroll
    for (int j = 0; j < 16; j++) comb[j * 256 + cbase] = o1[j];
  }
  __syncthreads();
  if (!half) {
#pragma unroll
    for (int j = 0; j < 16; j++) o1[j] += comb[j * 256 + cbase];

    float l = l_run + __shfl_xor(l_run, 32);
    float inv = 1.0f / l;
    const int b = bh >> 4, h = bh & 15;
    const int q = q0 + qw * 32 + l31;
    bf16* orow = AO + (size_t)(b * Tn + q) * Cn + h * Dn;
#pragma unroll
    for (int dt = 0; dt < 2; dt++) {
      const f32x16& oo = dt ? o1 : o0;
#pragma unroll
      for (int rq = 0; rq < 4; rq++) {
        bf16x4 ov = {(bf16)(oo[rq * 4 + 0] * inv), (bf16)(oo[rq * 4 + 1] * inv),
                     (bf16)(oo[rq * 4 + 2] * inv), (bf16)(oo[rq * 4 + 3] * inv)};
        *(bf16x4*)&orow[dt * 32 + rq * 8 + hi * 4] = ov;
      }
    }
  }
}

extern "C" void kernel_launch(void* const* d_in, const int* in_sizes, int n_in,
                              void* d_out, int out_size, void* d_ws, size_t ws_size,
                              hipStream_t stream) {
  const float* query = (const float*)d_in[0];
  const float* key   = (const float*)d_in[1];
  const float* value = (const float*)d_in[2];
  const float* Wq = (const float*)d_in[3];
  const float* bq = (const float*)d_in[4];
  const float* Wk = (const float*)d_in[5];
  const float* bk = (const float*)d_in[6];
  const float* Wv = (const float*)d_in[7];
  const float* bv = (const float*)d_in[8];
  const float* Wo = (const float*)d_in[9];
  const float* bo = (const float*)d_in[10];

  bf16* p = (bf16*)d_ws;
  bf16* WqT = p; p += WSZ;
  bf16* WkT = p; p += WSZ;
  bf16* WvT = p; p += WSZ;
  bf16* WoT = p; p += WSZ;
  bf16* Xbf = p; p += 3 * XSZ;   // bf16 activations; reused as AO after QKV GEMM
  bf16* Qh = p; p += XSZ;
  bf16* Kh = p; p += XSZ;
  bf16* VhT = p; p += XSZ;
  bf16* AO = Xbf;

  PrepArgs pa;
  pa.W[0] = Wq; pa.W[1] = Wk; pa.W[2] = Wv; pa.W[3] = Wo;
  pa.Wt[0] = WqT; pa.Wt[1] = WkT; pa.Wt[2] = WvT; pa.Wt[3] = WoT;
  pa.src[0] = query; pa.src[1] = key; pa.src[2] = value;
  pa.dst = Xbf;
  prep_kernel<<<dim3(6144 + 4096), 256, 0, stream>>>(pa);

  GemmArgs ga;
  ga.A[0] = Xbf; ga.A[1] = Xbf + XSZ; ga.A[2] = Xbf + 2 * XSZ;
  ga.Bt[0] = WqT;  ga.Bt[1] = WkT; ga.Bt[2] = WvT;
  ga.bias[0] = bq; ga.bias[1] = bk; ga.bias[2] = bv;
  ga.out[0] = Qh;  ga.out[1] = Kh;  ga.out[2] = VhT;
  ga.scale[0] = 0.125f * LOG2E; ga.scale[1] = 1.0f; ga.scale[2] = 1.0f;
  ga.layout[0] = 1; ga.layout[1] = 1; ga.layout[2] = 2;
  gemm_kernel<128><<<dim3(Cn / 128, Mn / 128, 3), 256, 0, stream>>>(ga, Cn);

  attn_kernel<<<dim3(512), 512, 0, stream>>>(Qh, Kh, VhT, AO);

  GemmArgs gb;
  gb.A[0] = AO; gb.Bt[0] = WoT; gb.bias[0] = bo; gb.out[0] = d_out; gb.scale[0] = 1.0f;
  gb.layout[0] = 0;
  gb.A[1] = gb.A[2] = nullptr; gb.Bt[1] = gb.Bt[2] = nullptr;
  gb.bias[1] = gb.bias[2] = nullptr; gb.out[1] = gb.out[2] = nullptr;
  gb.scale[1] = gb.scale[2] = 1.0f; gb.layout[1] = gb.layout[2] = 0;
  gemm_kernel<64><<<dim3(Cn / 128, Mn / 64, 1), 256, 0, stream>>>(gb, Cn);
}

// Round 15
// 215.801 us; speedup vs baseline: 1.0181x; 1.0056x over previous
//
#include <hip/hip_runtime.h>
#include <hip/hip_bf16.h>

typedef __bf16 bf16;
typedef __attribute__((ext_vector_type(8))) __bf16 bf16x8;
typedef __attribute__((ext_vector_type(4))) __bf16 bf16x4;
typedef __attribute__((ext_vector_type(4))) float f32x4;
typedef __attribute__((ext_vector_type(16))) float f32x16;
typedef __attribute__((ext_vector_type(4))) unsigned int u32x4;

#define MFMA16(a, b, c) __builtin_amdgcn_mfma_f32_16x16x32_bf16((a), (b), (c), 0, 0, 0)
#define MFMA32(a, b, c) __builtin_amdgcn_mfma_f32_32x32x16_bf16((a), (b), (c), 0, 0, 0)

constexpr int Bn = 2, Tn = 2048, Cn = 1024, Hn = 16, Dn = 64;
constexpr int Mn = Bn * Tn;
constexpr int WSZ = Cn * Cn;
constexpr int XSZ = Mn * Cn;
constexpr float LOG2E = 1.44269504088896f;

// async global->LDS, 16B/lane: LDS dest = wave-uniform base + lane*16
__device__ __forceinline__ void async_cp16(bf16* lds, const bf16* g) {
  __builtin_amdgcn_global_load_lds(
      (const __attribute__((address_space(1))) unsigned int*)g,
      (__attribute__((address_space(3))) unsigned int*)lds, 16, 0, 0);
}

__device__ __forceinline__ unsigned int cvtpk(float lo, float hi) {
  unsigned int r;
  asm("v_cvt_pk_bf16_f32 %0, %1, %2" : "=v"(r) : "v"(lo), "v"(hi));
  return r;
}

struct GemmArgs {
  const bf16* A[3];
  const bf16* Bt[3];
  const float* bias[3];
  void* out[3];
  float scale[3];
  int layout[3];   // 0 = fp32 [M,N]; 1 = bf16 [B,H,T,D]; 2 = bf16 [B,H,D,T]
};

struct PrepArgs {
  const float* W[4];
  bf16* Wt[4];
  const float* src[3];
  bf16* dst;
};

// ---------------- fused prep: activations fp32->bf16 + W transpose ----------------
__global__ __launch_bounds__(256) void prep_kernel(PrepArgs pa) {
  __shared__ float tile[32][33];
  const int id = blockIdx.x;
  const int tid = threadIdx.x;
  if (id < 6144) {
    const int z = id >> 11;
    const float* __restrict__ s = pa.src[z];
    size_t idx = ((size_t)(id & 2047) * 256 + tid) * 8;
    float4 a = *(const float4*)&s[idx];
    float4 b = *(const float4*)&s[idx + 4];
    bf16x8 o = {(bf16)a.x, (bf16)a.y, (bf16)a.z, (bf16)a.w,
                (bf16)b.x, (bf16)b.y, (bf16)b.z, (bf16)b.w};
    *(bf16x8*)&pa.dst[(size_t)z * XSZ + idx] = o;
  } else {
    const int t = id - 6144;        // 0..4095
    const int z = t >> 10;
    const int rem = t & 1023;
    const int bxp = rem & 31, byp = rem >> 5;
    const float* __restrict__ W = pa.W[z];
    bf16* __restrict__ Wt = pa.Wt[z];
    const int tx = tid & 31, ty = tid >> 5;   // (32,8)
    const int x = bxp * 32 + tx;
    const int y0 = byp * 32;
    for (int j = 0; j < 32; j += 8) tile[ty + j][tx] = W[(y0 + ty + j) * Cn + x];
    __syncthreads();
    const int n0 = bxp * 32;
    const int k = byp * 32 + tx;
    for (int j = 0; j < 32; j += 8)
      Wt[(n0 + ty + j) * Cn + k] = (bf16)tile[tx][ty + j];
  }
}

// ---------------- GEMM: C[M,N] = A[M,K] @ Wt[N,K]^T + bias ----------------
// BM x 128 tile, BK=64, async 16B staging, XOR chunk swizzle.
// v14 (kept): y-chunked XCD swizzle (T1) — FETCH 101MB->37MB verified.
// v17 = REVERT of v16's double-buffer. v16 measured: LDS 64KB halved
// residency (Occupancy 29->14%) and the QKV gemm went ~40->49.2us. The
// staging latency was already hidden by cross-block TLP at 2.4 blocks/CU;
// doubling LDS destroyed that TLP for an intra-wave overlap worth less
// (m132 lesson / Common-mistake #5). Single-buffer 2-barrier restored.
template <int BM>
__global__ __launch_bounds__(256) void gemm_kernel(GemmArgs args, int K) {
  constexpr int MT = BM / 32;          // m-tiles per wave
  const int z = blockIdx.z;
  const bf16* __restrict__ A = args.A[z];
  const bf16* __restrict__ Bt = args.Bt[z];
  const float* __restrict__ bias = args.bias[z];
  const float scale = args.scale[z];
  const int layout = args.layout[z];

  __shared__ bf16 As[BM * 64];
  __shared__ bf16 Bs[128 * 64];

  const int tid = threadIdx.x;
  const int w = tid >> 6, lane = tid & 63;
  const int wm = w >> 1, wn = w & 1;
  const int g = lane >> 4, l15 = lane & 15;
  const int r8 = lane >> 3, c8 = lane & 7;
  const int soff = (c8 ^ r8) << 3;
  const int kk = l15 & 7;
  const int off0 = (g ^ kk) << 3;
  const int off1 = ((4 + g) ^ kk) << 3;

  // y-chunked XCD swizzle: xcd = raw_id % 8 owns logical ids
  // [xcd*cpx, (xcd+1)*cpx) enumerated x-major -> contiguous y-rows per XCD.
  const int nx = gridDim.x;
  const int nwg = nx * gridDim.y;
  const int raw = blockIdx.x + nx * blockIdx.y;
  const int cpx = nwg >> 3;
  const int logical = (raw & 7) * cpx + (raw >> 3);
  const int bx = logical % nx, by = logical / nx;
  const int m0 = by * BM, n0 = bx * 128;

  f32x4 acc[MT][4] = {};

  for (int k0 = 0; k0 < K; k0 += 64) {
    __syncthreads();
    for (int i = 0; i < BM / 32; i++) {
      int p = w * (BM / 32) + i;
      async_cp16(&As[p * 512], &A[(size_t)(m0 + p * 8 + r8) * K + k0 + soff]);
    }
    for (int i = 0; i < 4; i++) {
      int p = w * 4 + i;
      async_cp16(&Bs[p * 512], &Bt[(size_t)(n0 + p * 8 + r8) * K + k0 + soff]);
    }
    __syncthreads();

    for (int ks = 0; ks < 2; ks++) {
      const int off = ks ? off1 : off0;
      bf16x8 af[MT], bfr[4];
      for (int mt = 0; mt < MT; mt++)
        af[mt] = *(const bf16x8*)&As[(wm * (BM / 2) + mt * 16 + l15) * 64 + off];
      for (int nt = 0; nt < 4; nt++)
        bfr[nt] = *(const bf16x8*)&Bs[(wn * 64 + nt * 16 + l15) * 64 + off];
      for (int mt = 0; mt < MT; mt++)
        for (int nt = 0; nt < 4; nt++)
          acc[mt][nt] = MFMA16(af[mt], bfr[nt], acc[mt][nt]);
    }
  }

  // epilogue: C/D layout row=(lane>>4)*4+r, col=lane&15
  for (int mt = 0; mt < MT; mt++) {
    for (int nt = 0; nt < 4; nt++) {
      int gn = n0 + wn * 64 + nt * 16 + l15;
      float bb = bias[gn];
      int gm0 = m0 + wm * (BM / 2) + mt * 16 + g * 4;
      float v[4];
      for (int r = 0; r < 4; r++) v[r] = (acc[mt][nt][r] + bb) * scale;
      if (layout == 2) {
        // V^T: bf16 [B,H,D,T]; r -> consecutive t
        int b = gm0 >> 11, t = gm0 & 2047, h = gn >> 6, d = gn & 63;
        bf16x4 ov = {(bf16)v[0], (bf16)v[1], (bf16)v[2], (bf16)v[3]};
        *(bf16x4*)&((bf16*)args.out[z])[(size_t)((b * Hn + h) * Dn + d) * Tn + t] = ov;
      } else if (layout == 1) {
        int b = gm0 >> 11, t = gm0 & 2047, h = gn >> 6, d = gn & 63;
        bf16* o = (bf16*)args.out[z] + (size_t)((b * Hn + h) * Tn + t) * Dn + d;
        for (int r = 0; r < 4; r++) o[(size_t)r * Dn] = (bf16)v[r];
      } else {
        float* o = (float*)args.out[z] + (size_t)gm0 * Cn + gn;
        for (int r = 0; r < 4; r++) o[(size_t)r * Cn] = v[r];
      }
    }
  }
}

// ---------------- Flash attention v15 (unchanged) ----------------
// v15 measured: V-swizzle fix halved SQ_LDS_BANK_CONFLICT (8.39M->4.19M) but
// attn only -0.6us -> conflicts off critical path. Wall = partially-overlapped
// trans(exp2 ~27us/CU) + VALU + LDS chains; near structural floor. Parked.
constexpr int KVB = 32;
constexpr int NTt = Tn / KVB;   // 64 kv tiles total; 32 per half

struct PvOn  { static constexpr bool value = true;  };
struct PvOff { static constexpr bool value = false; };

__global__ __launch_bounds__(512) void attn_kernel(const bf16* __restrict__ Qh,
                                                   const bf16* __restrict__ Kh,
                                                   const bf16* __restrict__ VhT,
                                                   bf16* __restrict__ AO) {
  __shared__ char smem[32768];   // per half (16KB): K[2][2048] | V[2][2048]; reused as combine buf

  const int tid = threadIdx.x;
  const int w = tid >> 6, lane = tid & 63;
  const int qw = w & 3, half = w >> 2;
  const int l31 = lane & 31, hi = lane >> 5;
  const int id = blockIdx.x;
  const int bh = id & 31;           // low bits -> same-bh blocks share an XCD
  const int q0 = (id >> 5) * 128;
  const int t0 = half * (NTt / 2);
  const int tend = t0 + NTt / 2;
  const size_t hb = (size_t)bh * Tn * Dn;
  const size_t hbT = (size_t)bh * Dn * Tn;
  // K staging: lane -> rel row r8 = lane>>3 (8 rows/wave), chunk c8 = lane&7
  const int r8 = lane >> 3, c8 = lane & 7;
  const int soff = (c8 ^ r8) << 3;              // K global chunk pre-swizzle
  // V staging: lane -> rel row rv = lane>>2 (16 rows/wave), chunk cv = lane&3
  const int rv = lane >> 2, cv = lane & 3;
  const int voff = ((cv ^ ((rv >> 1) & 3)) << 3);  // V pre-swizzle, f(row)=(row>>1)&3
  // K-frag read addressing: row r, chunk c at (r>>3)*512 + (r&7)*64 + ((c^(r&7))<<3)
  const int sw7 = l31 & 7;
  const int baseK = ((l31 >> 3) << 9) + (sw7 << 6);
  // V-frag read addressing: row r (=l31 / +32), chunk c at r*32 + ((c^((r>>1)&3))<<3)
  const int sw3 = (l31 >> 1) & 3;
  const int baseV = l31 << 5;

  bf16* Ks = (bf16*)(smem + half * 16384);            // [2][2048]
  bf16* Vt = (bf16*)(smem + half * 16384 + 8192);     // [2][2048]

  // Q fragments (B-operand): lane owns q = q0 + qw*32 + l31
  bf16x8 qf[4];
  {
    const bf16* qp = Qh + hb + (size_t)(q0 + qw * 32 + l31) * Dn + hi * 8;
#pragma unroll
    for (int ks = 0; ks < 4; ks++) qf[ks] = *(const bf16x8*)(qp + ks * 16);
  }

  f32x16 o0 = {}, o1 = {};
  float l_run = 0.f;
  bf16x8 vf0[2], vf1[2];   // V^T frags of tile t (d 0-31 / 32-63), consumed iter t+1
  bf16x8 pfv[2];           // P frags of tile t, consumed iter t+1

  // prologue: stage tile t0 into buffer 0 (2 loads/wave: 1 K + 1 V)
  async_cp16(&Ks[qw * 512], &Kh[hb + (size_t)(t0 * KVB + qw * 8 + r8) * Dn + soff]);
  async_cp16(&Vt[qw * 512], &VhT[hbT + (size_t)(qw * 16 + rv) * Tn + t0 * KVB + voff]);
  __syncthreads();

  auto body = [&](int kt, auto pvtag) {
    constexpr bool PV = decltype(pvtag)::value;
    const int cur = kt & 1;   // t0 is even for both halves
    if (kt + 1 < tend) {
      const int nxt = cur ^ 1;
      const int t1 = (kt + 1) * KVB;
      async_cp16(&Ks[nxt * 2048 + qw * 512], &Kh[hb + (size_t)(t1 + qw * 8 + r8) * Dn + soff]);
      async_cp16(&Vt[nxt * 2048 + qw * 512], &VhT[hbT + (size_t)(qw * 16 + rv) * Tn + t1 + voff]);
    }

    // S^T = K Q^T : 32 kv rows, lane col = its q
    f32x16 sA = {};
    const bf16* ksb = &Ks[cur * 2048];
    __builtin_amdgcn_s_setprio(1);
#pragma unroll
    for (int ks = 0; ks < 4; ks++) {
      bf16x8 kf = *(const bf16x8*)(ksb + baseK + (((ks * 2 + hi) ^ sw7) << 3));
      sA = MFMA32(kf, qf[ks], sA);
    }
    __builtin_amdgcn_s_setprio(0);

    // exp(t) interleaved with PV(t-1): independent streams keep VALU+MFMA fed
    float pe[16];
    float r0 = 0.f, r1 = 0.f;
#pragma unroll
    for (int gq = 0; gq < 4; gq++) {
      float e0 = __builtin_amdgcn_exp2f(sA[gq * 4 + 0]);
      float e1 = __builtin_amdgcn_exp2f(sA[gq * 4 + 1]);
      float e2 = __builtin_amdgcn_exp2f(sA[gq * 4 + 2]);
      float e3 = __builtin_amdgcn_exp2f(sA[gq * 4 + 3]);
      pe[gq * 4 + 0] = e0; pe[gq * 4 + 1] = e1;
      pe[gq * 4 + 2] = e2; pe[gq * 4 + 3] = e3;
      r0 += e0 + e1; r1 += e2 + e3;
      if constexpr (PV) {
        if (gq < 2) o0 = MFMA32(vf0[gq], pfv[gq], o0);
        else        o1 = MFMA32(vf1[gq - 2], pfv[gq - 2], o1);
      }
    }
    l_run += r0 + r1;

    // pack P in-register (v10 scheme, half quantity): pfv[0]=kv 0..15, pfv[1]=kv 16..31
    {
      unsigned a0 = cvtpk(pe[0], pe[1]),  a1 = cvtpk(pe[2], pe[3]);
      unsigned b0 = cvtpk(pe[4], pe[5]),  b1 = cvtpk(pe[6], pe[7]);
      auto s0 = __builtin_amdgcn_permlane32_swap(a0, b0, false, false);
      auto s1 = __builtin_amdgcn_permlane32_swap(a1, b1, false, false);
      u32x4 w0 = {s0[0], s1[0], s0[1], s1[1]};
      pfv[0] = __builtin_bit_cast(bf16x8, w0);
      a0 = cvtpk(pe[8], pe[9]);   a1 = cvtpk(pe[10], pe[11]);
      b0 = cvtpk(pe[12], pe[13]); b1 = cvtpk(pe[14], pe[15]);
      s0 = __builtin_amdgcn_permlane32_swap(a0, b0, false, false);
      s1 = __builtin_amdgcn_permlane32_swap(a1, b1, false, false);
      u32x4 w1 = {s0[0], s1[0], s0[1], s1[1]};
      pfv[1] = __builtin_bit_cast(bf16x8, w1);
    }

    // V^T frags for next iter's PV; latency hidden under barrier + next S
    {
      const bf16* vtb = &Vt[cur * 2048];
#pragma unroll
      for (int ks = 0; ks < 2; ks++) {
        const int off = (((ks * 2 + hi) ^ sw3) << 3);
        vf0[ks] = *(const bf16x8*)(vtb + baseV + off);
        vf1[ks] = *(const bf16x8*)(vtb + 1024 + baseV + off);
      }
    }

    __syncthreads();  // all waves done with cur buffers; drains prefetch vmcnt
  };

  body(t0, PvOff{});
  for (int kt = t0 + 1; kt < tend; kt++) body(kt, PvOn{});

  // epilogue PV for the last tile
  __builtin_amdgcn_s_setprio(1);
#pragma unroll
  for (int ks = 0; ks < 2; ks++) {
    o0 = MFMA32(vf0[ks], pfv[ks], o0);
    o1 = MFMA32(vf1[ks], pfv[ks], o1);
  }
  __builtin_amdgcn_s_setprio(0);

  // in-block combine, two phases (32KB LDS holds 17 fields of 256 f32 = 17KB)
  float* comb = (float*)smem;
  const int cbase = qw * 64 + lane;
  if (half) {
#pragma unroll
    for (int j = 0; j < 16; j++) comb[j * 256 + cbase] = o0[j];
    comb[16 * 256 + cbase] = l_run;
  }
  __syncthreads();
  if (!half) {
#pragma unroll
    for (int j = 0; j < 16; j++) o0[j] += comb[j * 256 + cbase];
    l_run += comb[16 * 256 + cbase];
  }
  __syncthreads();
  if (half) {
#pragma unroll
    for (int j = 0; j < 16; j++) comb[j * 256 + cbase] = o1[j];
  }
  __syncthreads();
  if (!half) {
#pragma unroll
    for (int j = 0; j < 16; j++) o1[j] += comb[j * 256 + cbase];

    float l = l_run + __shfl_xor(l_run, 32);
    float inv = 1.0f / l;
    const int b = bh >> 4, h = bh & 15;
    const int q = q0 + qw * 32 + l31;
    bf16* orow = AO + (size_t)(b * Tn + q) * Cn + h * Dn;
#pragma unroll
    for (int dt = 0; dt < 2; dt++) {
      const f32x16& oo = dt ? o1 : o0;
#pragma unroll
      for (int rq = 0; rq < 4; rq++) {
        bf16x4 ov = {(bf16)(oo[rq * 4 + 0] * inv), (bf16)(oo[rq * 4 + 1] * inv),
                     (bf16)(oo[rq * 4 + 2] * inv), (bf16)(oo[rq * 4 + 3] * inv)};
        *(bf16x4*)&orow[dt * 32 + rq * 8 + hi * 4] = ov;
      }
    }
  }
}

extern "C" void kernel_launch(void* const* d_in, const int* in_sizes, int n_in,
                              void* d_out, int out_size, void* d_ws, size_t ws_size,
                              hipStream_t stream) {
  const float* query = (const float*)d_in[0];
  const float* key   = (const float*)d_in[1];
  const float* value = (const float*)d_in[2];
  const float* Wq = (const float*)d_in[3];
  const float* bq = (const float*)d_in[4];
  const float* Wk = (const float*)d_in[5];
  const float* bk = (const float*)d_in[6];
  const float* Wv = (const float*)d_in[7];
  const float* bv = (const float*)d_in[8];
  const float* Wo = (const float*)d_in[9];
  const float* bo = (const float*)d_in[10];

  bf16* p = (bf16*)d_ws;
  bf16* WqT = p; p += WSZ;
  bf16* WkT = p; p += WSZ;
  bf16* WvT = p; p += WSZ;
  bf16* WoT = p; p += WSZ;
  bf16* Xbf = p; p += 3 * XSZ;   // bf16 activations; reused as AO after QKV GEMM
  bf16* Qh = p; p += XSZ;
  bf16* Kh = p; p += XSZ;
  bf16* VhT = p; p += XSZ;
  bf16* AO = Xbf;

  PrepArgs pa;
  pa.W[0] = Wq; pa.W[1] = Wk; pa.W[2] = Wv; pa.W[3] = Wo;
  pa.Wt[0] = WqT; pa.Wt[1] = WkT; pa.Wt[2] = WvT; pa.Wt[3] = WoT;
  pa.src[0] = query; pa.src[1] = key; pa.src[2] = value;
  pa.dst = Xbf;
  prep_kernel<<<dim3(6144 + 4096), 256, 0, stream>>>(pa);

  GemmArgs ga;
  ga.A[0] = Xbf; ga.A[1] = Xbf + XSZ; ga.A[2] = Xbf + 2 * XSZ;
  ga.Bt[0] = WqT;  ga.Bt[1] = WkT; ga.Bt[2] = WvT;
  ga.bias[0] = bq; ga.bias[1] = bk; ga.bias[2] = bv;
  ga.out[0] = Qh;  ga.out[1] = Kh;  ga.out[2] = VhT;
  ga.scale[0] = 0.125f * LOG2E; ga.scale[1] = 1.0f; ga.scale[2] = 1.0f;
  ga.layout[0] = 1; ga.layout[1] = 1; ga.layout[2] = 2;
  gemm_kernel<128><<<dim3(Cn / 128, Mn / 128, 3), 256, 0, stream>>>(ga, Cn);

  attn_kernel<<<dim3(512), 512, 0, stream>>>(Qh, Kh, VhT, AO);

  GemmArgs gb;
  gb.A[0] = AO; gb.Bt[0] = WoT; gb.bias[0] = bo; gb.out[0] = d_out; gb.scale[0] = 1.0f;
  gb.layout[0] = 0;
  gb.A[1] = gb.A[2] = nullptr; gb.Bt[1] = gb.Bt[2] = nullptr;
  gb.bias[1] = gb.bias[2] = nullptr; gb.out[1] = gb.out[2] = nullptr;
  gb.scale[1] = gb.scale[2] = 1.0f; gb.layout[1] = gb.layout[2] = 0;
  gemm_kernel<64><<<dim3(Cn / 128, Mn / 64, 1), 256, 0, stream>>>(gb, Cn);
}

// Round 16
// 214.473 us; speedup vs baseline: 1.0244x; 1.0062x over previous
//
#include <hip/hip_runtime.h>
#include <hip/hip_bf16.h>

typedef __bf16 bf16;
typedef __attribute__((ext_vector_type(8))) __bf16 bf16x8;
typedef __attribute__((ext_vector_type(4))) __bf16 bf16x4;
typedef __attribute__((ext_vector_type(4))) float f32x4;
typedef __attribute__((ext_vector_type(16))) float f32x16;
typedef __attribute__((ext_vector_type(4))) unsigned int u32x4;

#define MFMA16(a, b, c) __builtin_amdgcn_mfma_f32_16x16x32_bf16((a), (b), (c), 0, 0, 0)
#define MFMA32(a, b, c) __builtin_amdgcn_mfma_f32_32x32x16_bf16((a), (b), (c), 0, 0, 0)

constexpr int Bn = 2, Tn = 2048, Cn = 1024, Hn = 16, Dn = 64;
constexpr int Mn = Bn * Tn;
constexpr int WSZ = Cn * Cn;
constexpr int XSZ = Mn * Cn;
constexpr float LOG2E = 1.44269504088896f;

// async global->LDS, 16B/lane: LDS dest = wave-uniform base + lane*16
__device__ __forceinline__ void async_cp16(bf16* lds, const bf16* g) {
  __builtin_amdgcn_global_load_lds(
      (const __attribute__((address_space(1))) unsigned int*)g,
      (__attribute__((address_space(3))) unsigned int*)lds, 16, 0, 0);
}

__device__ __forceinline__ unsigned int cvtpk(float lo, float hi) {
  unsigned int r;
  asm("v_cvt_pk_bf16_f32 %0, %1, %2" : "=v"(r) : "v"(lo), "v"(hi));
  return r;
}

struct GemmArgs {
  const bf16* A[3];
  const bf16* Bt[3];
  const float* bias[3];
  void* out[3];
  float scale[3];
  int layout[3];   // 0 = fp32 [M,N]; 1 = bf16 [B,H,T,D]; 2 = bf16 [B,H,D,T]
};

struct PrepArgs {
  const float* W[4];
  bf16* Wt[4];
  const float* src[3];
  bf16* dst;
};

// ---------------- fused prep: activations fp32->bf16 + W transpose ----------------
__global__ __launch_bounds__(256) void prep_kernel(PrepArgs pa) {
  __shared__ float tile[32][33];
  const int id = blockIdx.x;
  const int tid = threadIdx.x;
  if (id < 6144) {
    const int z = id >> 11;
    const float* __restrict__ s = pa.src[z];
    size_t idx = ((size_t)(id & 2047) * 256 + tid) * 8;
    float4 a = *(const float4*)&s[idx];
    float4 b = *(const float4*)&s[idx + 4];
    bf16x8 o = {(bf16)a.x, (bf16)a.y, (bf16)a.z, (bf16)a.w,
                (bf16)b.x, (bf16)b.y, (bf16)b.z, (bf16)b.w};
    *(bf16x8*)&pa.dst[(size_t)z * XSZ + idx] = o;
  } else {
    const int t = id - 6144;        // 0..4095
    const int z = t >> 10;
    const int rem = t & 1023;
    const int bxp = rem & 31, byp = rem >> 5;
    const float* __restrict__ W = pa.W[z];
    bf16* __restrict__ Wt = pa.Wt[z];
    const int tx = tid & 31, ty = tid >> 5;   // (32,8)
    const int x = bxp * 32 + tx;
    const int y0 = byp * 32;
    for (int j = 0; j < 32; j += 8) tile[ty + j][tx] = W[(y0 + ty + j) * Cn + x];
    __syncthreads();
    const int n0 = bxp * 32;
    const int k = byp * 32 + tx;
    for (int j = 0; j < 32; j += 8)
      Wt[(n0 + ty + j) * Cn + k] = (bf16)tile[tx][ty + j];
  }
}

// ---------------- GEMM: C[M,N] = A[M,K] @ Wt[N,K]^T + bias ----------------
// BM x 128 tile, BK=64, async 16B staging, XOR chunk swizzle.
// v14 (kept): y-chunked XCD swizzle (T1) — FETCH 101MB->37MB verified.
// v17 (kept): single-buffer 2-barrier (v16's dbuf halved residency, -20%).
// v18: QKV GEMM BM 128->64. v16 established the regime: latency-bound,
// TLP-starved at 2.4 blocks/CU. BM=64 -> LDS 24KB, VGPR ~80 -> ~6 blocks/CU
// (2.5x TLP) with the SAME sync structure. Proj (BM=64 already) measures
// >=660 TF = BM=128's 645, so per-block MFMA density loss is free here.
// Launch-site change only; template path already exercised by proj.
template <int BM>
__global__ __launch_bounds__(256) void gemm_kernel(GemmArgs args, int K) {
  constexpr int MT = BM / 32;          // m-tiles per wave
  const int z = blockIdx.z;
  const bf16* __restrict__ A = args.A[z];
  const bf16* __restrict__ Bt = args.Bt[z];
  const float* __restrict__ bias = args.bias[z];
  const float scale = args.scale[z];
  const int layout = args.layout[z];

  __shared__ bf16 As[BM * 64];
  __shared__ bf16 Bs[128 * 64];

  const int tid = threadIdx.x;
  const int w = tid >> 6, lane = tid & 63;
  const int wm = w >> 1, wn = w & 1;
  const int g = lane >> 4, l15 = lane & 15;
  const int r8 = lane >> 3, c8 = lane & 7;
  const int soff = (c8 ^ r8) << 3;
  const int kk = l15 & 7;
  const int off0 = (g ^ kk) << 3;
  const int off1 = ((4 + g) ^ kk) << 3;

  // y-chunked XCD swizzle: xcd = raw_id % 8 owns logical ids
  // [xcd*cpx, (xcd+1)*cpx) enumerated x-major -> contiguous y-rows per XCD.
  const int nx = gridDim.x;
  const int nwg = nx * gridDim.y;
  const int raw = blockIdx.x + nx * blockIdx.y;
  const int cpx = nwg >> 3;
  const int logical = (raw & 7) * cpx + (raw >> 3);
  const int bx = logical % nx, by = logical / nx;
  const int m0 = by * BM, n0 = bx * 128;

  f32x4 acc[MT][4] = {};

  for (int k0 = 0; k0 < K; k0 += 64) {
    __syncthreads();
    for (int i = 0; i < BM / 32; i++) {
      int p = w * (BM / 32) + i;
      async_cp16(&As[p * 512], &A[(size_t)(m0 + p * 8 + r8) * K + k0 + soff]);
    }
    for (int i = 0; i < 4; i++) {
      int p = w * 4 + i;
      async_cp16(&Bs[p * 512], &Bt[(size_t)(n0 + p * 8 + r8) * K + k0 + soff]);
    }
    __syncthreads();

    for (int ks = 0; ks < 2; ks++) {
      const int off = ks ? off1 : off0;
      bf16x8 af[MT], bfr[4];
      for (int mt = 0; mt < MT; mt++)
        af[mt] = *(const bf16x8*)&As[(wm * (BM / 2) + mt * 16 + l15) * 64 + off];
      for (int nt = 0; nt < 4; nt++)
        bfr[nt] = *(const bf16x8*)&Bs[(wn * 64 + nt * 16 + l15) * 64 + off];
      for (int mt = 0; mt < MT; mt++)
        for (int nt = 0; nt < 4; nt++)
          acc[mt][nt] = MFMA16(af[mt], bfr[nt], acc[mt][nt]);
    }
  }

  // epilogue: C/D layout row=(lane>>4)*4+r, col=lane&15
  for (int mt = 0; mt < MT; mt++) {
    for (int nt = 0; nt < 4; nt++) {
      int gn = n0 + wn * 64 + nt * 16 + l15;
      float bb = bias[gn];
      int gm0 = m0 + wm * (BM / 2) + mt * 16 + g * 4;
      float v[4];
      for (int r = 0; r < 4; r++) v[r] = (acc[mt][nt][r] + bb) * scale;
      if (layout == 2) {
        // V^T: bf16 [B,H,D,T]; r -> consecutive t
        int b = gm0 >> 11, t = gm0 & 2047, h = gn >> 6, d = gn & 63;
        bf16x4 ov = {(bf16)v[0], (bf16)v[1], (bf16)v[2], (bf16)v[3]};
        *(bf16x4*)&((bf16*)args.out[z])[(size_t)((b * Hn + h) * Dn + d) * Tn + t] = ov;
      } else if (layout == 1) {
        int b = gm0 >> 11, t = gm0 & 2047, h = gn >> 6, d = gn & 63;
        bf16* o = (bf16*)args.out[z] + (size_t)((b * Hn + h) * Tn + t) * Dn + d;
        for (int r = 0; r < 4; r++) o[(size_t)r * Dn] = (bf16)v[r];
      } else {
        float* o = (float*)args.out[z] + (size_t)gm0 * Cn + gn;
        for (int r = 0; r < 4; r++) o[(size_t)r * Cn] = v[r];
      }
    }
  }
}

// ---------------- Flash attention v15 (unchanged) ----------------
// v15 measured: V-swizzle fix halved SQ_LDS_BANK_CONFLICT (8.39M->4.19M) but
// attn only -0.6us -> conflicts off critical path. Wall = partially-overlapped
// trans(exp2) + VALU + LDS chains; near structural floor. Parked.
constexpr int KVB = 32;
constexpr int NTt = Tn / KVB;   // 64 kv tiles total; 32 per half

struct PvOn  { static constexpr bool value = true;  };
struct PvOff { static constexpr bool value = false; };

__global__ __launch_bounds__(512) void attn_kernel(const bf16* __restrict__ Qh,
                                                   const bf16* __restrict__ Kh,
                                                   const bf16* __restrict__ VhT,
                                                   bf16* __restrict__ AO) {
  __shared__ char smem[32768];   // per half (16KB): K[2][2048] | V[2][2048]; reused as combine buf

  const int tid = threadIdx.x;
  const int w = tid >> 6, lane = tid & 63;
  const int qw = w & 3, half = w >> 2;
  const int l31 = lane & 31, hi = lane >> 5;
  const int id = blockIdx.x;
  const int bh = id & 31;           // low bits -> same-bh blocks share an XCD
  const int q0 = (id >> 5) * 128;
  const int t0 = half * (NTt / 2);
  const int tend = t0 + NTt / 2;
  const size_t hb = (size_t)bh * Tn * Dn;
  const size_t hbT = (size_t)bh * Dn * Tn;
  // K staging: lane -> rel row r8 = lane>>3 (8 rows/wave), chunk c8 = lane&7
  const int r8 = lane >> 3, c8 = lane & 7;
  const int soff = (c8 ^ r8) << 3;              // K global chunk pre-swizzle
  // V staging: lane -> rel row rv = lane>>2 (16 rows/wave), chunk cv = lane&3
  const int rv = lane >> 2, cv = lane & 3;
  const int voff = ((cv ^ ((rv >> 1) & 3)) << 3);  // V pre-swizzle, f(row)=(row>>1)&3
  // K-frag read addressing: row r, chunk c at (r>>3)*512 + (r&7)*64 + ((c^(r&7))<<3)
  const int sw7 = l31 & 7;
  const int baseK = ((l31 >> 3) << 9) + (sw7 << 6);
  // V-frag read addressing: row r (=l31 / +32), chunk c at r*32 + ((c^((r>>1)&3))<<3)
  const int sw3 = (l31 >> 1) & 3;
  const int baseV = l31 << 5;

  bf16* Ks = (bf16*)(smem + half * 16384);            // [2][2048]
  bf16* Vt = (bf16*)(smem + half * 16384 + 8192);     // [2][2048]

  // Q fragments (B-operand): lane owns q = q0 + qw*32 + l31
  bf16x8 qf[4];
  {
    const bf16* qp = Qh + hb + (size_t)(q0 + qw * 32 + l31) * Dn + hi * 8;
#pragma unroll
    for (int ks = 0; ks < 4; ks++) qf[ks] = *(const bf16x8*)(qp + ks * 16);
  }

  f32x16 o0 = {}, o1 = {};
  float l_run = 0.f;
  bf16x8 vf0[2], vf1[2];   // V^T frags of tile t (d 0-31 / 32-63), consumed iter t+1
  bf16x8 pfv[2];           // P frags of tile t, consumed iter t+1

  // prologue: stage tile t0 into buffer 0 (2 loads/wave: 1 K + 1 V)
  async_cp16(&Ks[qw * 512], &Kh[hb + (size_t)(t0 * KVB + qw * 8 + r8) * Dn + soff]);
  async_cp16(&Vt[qw * 512], &VhT[hbT + (size_t)(qw * 16 + rv) * Tn + t0 * KVB + voff]);
  __syncthreads();

  auto body = [&](int kt, auto pvtag) {
    constexpr bool PV = decltype(pvtag)::value;
    const int cur = kt & 1;   // t0 is even for both halves
    if (kt + 1 < tend) {
      const int nxt = cur ^ 1;
      const int t1 = (kt + 1) * KVB;
      async_cp16(&Ks[nxt * 2048 + qw * 512], &Kh[hb + (size_t)(t1 + qw * 8 + r8) * Dn + soff]);
      async_cp16(&Vt[nxt * 2048 + qw * 512], &VhT[hbT + (size_t)(qw * 16 + rv) * Tn + t1 + voff]);
    }

    // S^T = K Q^T : 32 kv rows, lane col = its q
    f32x16 sA = {};
    const bf16* ksb = &Ks[cur * 2048];
    __builtin_amdgcn_s_setprio(1);
#pragma unroll
    for (int ks = 0; ks < 4; ks++) {
      bf16x8 kf = *(const bf16x8*)(ksb + baseK + (((ks * 2 + hi) ^ sw7) << 3));
      sA = MFMA32(kf, qf[ks], sA);
    }
    __builtin_amdgcn_s_setprio(0);

    // exp(t) interleaved with PV(t-1): independent streams keep VALU+MFMA fed
    float pe[16];
    float r0 = 0.f, r1 = 0.f;
#pragma unroll
    for (int gq = 0; gq < 4; gq++) {
      float e0 = __builtin_amdgcn_exp2f(sA[gq * 4 + 0]);
      float e1 = __builtin_amdgcn_exp2f(sA[gq * 4 + 1]);
      float e2 = __builtin_amdgcn_exp2f(sA[gq * 4 + 2]);
      float e3 = __builtin_amdgcn_exp2f(sA[gq * 4 + 3]);
      pe[gq * 4 + 0] = e0; pe[gq * 4 + 1] = e1;
      pe[gq * 4 + 2] = e2; pe[gq * 4 + 3] = e3;
      r0 += e0 + e1; r1 += e2 + e3;
      if constexpr (PV) {
        if (gq < 2) o0 = MFMA32(vf0[gq], pfv[gq], o0);
        else        o1 = MFMA32(vf1[gq - 2], pfv[gq - 2], o1);
      }
    }
    l_run += r0 + r1;

    // pack P in-register (v10 scheme, half quantity): pfv[0]=kv 0..15, pfv[1]=kv 16..31
    {
      unsigned a0 = cvtpk(pe[0], pe[1]),  a1 = cvtpk(pe[2], pe[3]);
      unsigned b0 = cvtpk(pe[4], pe[5]),  b1 = cvtpk(pe[6], pe[7]);
      auto s0 = __builtin_amdgcn_permlane32_swap(a0, b0, false, false);
      auto s1 = __builtin_amdgcn_permlane32_swap(a1, b1, false, false);
      u32x4 w0 = {s0[0], s1[0], s0[1], s1[1]};
      pfv[0] = __builtin_bit_cast(bf16x8, w0);
      a0 = cvtpk(pe[8], pe[9]);   a1 = cvtpk(pe[10], pe[11]);
      b0 = cvtpk(pe[12], pe[13]); b1 = cvtpk(pe[14], pe[15]);
      s0 = __builtin_amdgcn_permlane32_swap(a0, b0, false, false);
      s1 = __builtin_amdgcn_permlane32_swap(a1, b1, false, false);
      u32x4 w1 = {s0[0], s1[0], s0[1], s1[1]};
      pfv[1] = __builtin_bit_cast(bf16x8, w1);
    }

    // V^T frags for next iter's PV; latency hidden under barrier + next S
    {
      const bf16* vtb = &Vt[cur * 2048];
#pragma unroll
      for (int ks = 0; ks < 2; ks++) {
        const int off = (((ks * 2 + hi) ^ sw3) << 3);
        vf0[ks] = *(const bf16x8*)(vtb + baseV + off);
        vf1[ks] = *(const bf16x8*)(vtb + 1024 + baseV + off);
      }
    }

    __syncthreads();  // all waves done with cur buffers; drains prefetch vmcnt
  };

  body(t0, PvOff{});
  for (int kt = t0 + 1; kt < tend; kt++) body(kt, PvOn{});

  // epilogue PV for the last tile
  __builtin_amdgcn_s_setprio(1);
#pragma unroll
  for (int ks = 0; ks < 2; ks++) {
    o0 = MFMA32(vf0[ks], pfv[ks], o0);
    o1 = MFMA32(vf1[ks], pfv[ks], o1);
  }
  __builtin_amdgcn_s_setprio(0);

  // in-block combine, two phases (32KB LDS holds 17 fields of 256 f32 = 17KB)
  float* comb = (float*)smem;
  const int cbase = qw * 64 + lane;
  if (half) {
#pragma unroll
    for (int j = 0; j < 16; j++) comb[j * 256 + cbase] = o0[j];
    comb[16 * 256 + cbase] = l_run;
  }
  __syncthreads();
  if (!half) {
#pragma unroll
    for (int j = 0; j < 16; j++) o0[j] += comb[j * 256 + cbase];
    l_run += comb[16 * 256 + cbase];
  }
  __syncthreads();
  if (half) {
#pragma unroll
    for (int j = 0; j < 16; j++) comb[j * 256 + cbase] = o1[j];
  }
  __syncthreads();
  if (!half) {
#pragma unroll
    for (int j = 0; j < 16; j++) o1[j] += comb[j * 256 + cbase];

    float l = l_run + __shfl_xor(l_run, 32);
    float inv = 1.0f / l;
    const int b = bh >> 4, h = bh & 15;
    const int q = q0 + qw * 32 + l31;
    bf16* orow = AO + (size_t)(b * Tn + q) * Cn + h * Dn;
#pragma unroll
    for (int dt = 0; dt < 2; dt++) {
      const f32x16& oo = dt ? o1 : o0;
#pragma unroll
      for (int rq = 0; rq < 4; rq++) {
        bf16x4 ov = {(bf16)(oo[rq * 4 + 0] * inv), (bf16)(oo[rq * 4 + 1] * inv),
                     (bf16)(oo[rq * 4 + 2] * inv), (bf16)(oo[rq * 4 + 3] * inv)};
        *(bf16x4*)&orow[dt * 32 + rq * 8 + hi * 4] = ov;
      }
    }
  }
}

extern "C" void kernel_launch(void* const* d_in, const int* in_sizes, int n_in,
                              void* d_out, int out_size, void* d_ws, size_t ws_size,
                              hipStream_t stream) {
  const float* query = (const float*)d_in[0];
  const float* key   = (const float*)d_in[1];
  const float* value = (const float*)d_in[2];
  const float* Wq = (const float*)d_in[3];
  const float* bq = (const float*)d_in[4];
  const float* Wk = (const float*)d_in[5];
  const float* bk = (const float*)d_in[6];
  const float* Wv = (const float*)d_in[7];
  const float* bv = (const float*)d_in[8];
  const float* Wo = (const float*)d_in[9];
  const float* bo = (const float*)d_in[10];

  bf16* p = (bf16*)d_ws;
  bf16* WqT = p; p += WSZ;
  bf16* WkT = p; p += WSZ;
  bf16* WvT = p; p += WSZ;
  bf16* WoT = p; p += WSZ;
  bf16* Xbf = p; p += 3 * XSZ;   // bf16 activations; reused as AO after QKV GEMM
  bf16* Qh = p; p += XSZ;
  bf16* Kh = p; p += XSZ;
  bf16* VhT = p; p += XSZ;
  bf16* AO = Xbf;

  PrepArgs pa;
  pa.W[0] = Wq; pa.W[1] = Wk; pa.W[2] = Wv; pa.W[3] = Wo;
  pa.Wt[0] = WqT; pa.Wt[1] = WkT; pa.Wt[2] = WvT; pa.Wt[3] = WoT;
  pa.src[0] = query; pa.src[1] = key; pa.src[2] = value;
  pa.dst = Xbf;
  prep_kernel<<<dim3(6144 + 4096), 256, 0, stream>>>(pa);

  GemmArgs ga;
  ga.A[0] = Xbf; ga.A[1] = Xbf + XSZ; ga.A[2] = Xbf + 2 * XSZ;
  ga.Bt[0] = WqT;  ga.Bt[1] = WkT; ga.Bt[2] = WvT;
  ga.bias[0] = bq; ga.bias[1] = bk; ga.bias[2] = bv;
  ga.out[0] = Qh;  ga.out[1] = Kh;  ga.out[2] = VhT;
  ga.scale[0] = 0.125f * LOG2E; ga.scale[1] = 1.0f; ga.scale[2] = 1.0f;
  ga.layout[0] = 1; ga.layout[1] = 1; ga.layout[2] = 2;
  gemm_kernel<64><<<dim3(Cn / 128, Mn / 64, 3), 256, 0, stream>>>(ga, Cn);

  attn_kernel<<<dim3(512), 512, 0, stream>>>(Qh, Kh, VhT, AO);

  GemmArgs gb;
  gb.A[0] = AO; gb.Bt[0] = WoT; gb.bias[0] = bo; gb.out[0] = d_out; gb.scale[0] = 1.0f;
  gb.layout[0] = 0;
  gb.A[1] = gb.A[2] = nullptr; gb.Bt[1] = gb.Bt[2] = nullptr;
  gb.bias[1] = gb.bias[2] = nullptr; gb.out[1] = gb.out[2] = nullptr;
  gb.scale[1] = gb.scale[2] = 1.0f; gb.layout[1] = gb.layout[2] = 0;
  gemm_kernel<64><<<dim3(Cn / 128, Mn / 64, 1), 256, 0, stream>>>(gb, Cn);
}